// Round 9
// baseline (150.456 us; speedup 1.0000x reference)
//
#include <hip/hip_runtime.h>

// SecConv2d over Z_{2^32} via i8 MFMA, 4-chain biased-operand scheme (exact).
//   s(x) = x_byte - 128 per limb  => X = s(al) + 256*s(ah) + 32896
//   s(w) likewise                 => W = s0 + 256*s1 + 32896
//   out = P00 + (P01+P10)<<8 + P11<<16 + 32896*Q[p] + K[k]   (mod 2^32)
//   Q = 3x3 box sum of S[p], S[p] = sum_c (X_true - 32896) (border cells are
//   bytes 0x80 == s=-128 -> uniformly "interior with x=0", exact).
//
// R18 == R17 resubmitted (previous round was an infra failure, no HW result).
// R17: split design. R14's counters (MfmaUtil 12%, VALUBusy 9%, HBM 21%,
// Occ 12.8%) showed the fused kernel is latency-bound, not issue-bound.
//  packx: stream x -> padded packed-global [n][58][58][128B] (borders 0x80
//         pre-filled) + padded S-plane [n][58][58]. Pure BW ~40MB.
//  conv:  NO LDS, NO barriers. B-fragments read straight from packed global
//         (cell layout byte-identical to the old LDS cell); taps = imm
//         offsets off 3 row pointers; Q = 9 imm-offset S loads. VGPR~140,
//         launch_bounds(256,3) -> 12 waves/CU (3x R14), grid 896.
//  Fallback to the proven R16 fused kernel if ws_size < 14.3 MB.

typedef int v4i __attribute__((ext_vector_type(4)));

#define LCOL 144               // fused-path LDS col stride
#define LROW (58 * LCOL)
#define PKROW (58 * 128)       // 7424 B per packed padded row
#define PKIMG (58 * PKROW)     // 430592 B per image
#define SIMG  (58 * 58)        // S-plane ints per image
#define WS_NEED (32L * PKIMG + 32L * SIMG * 4)

__device__ __align__(16) unsigned char g_wb[2 * 9 * 64 * 64];
__device__ unsigned g_off[64];

static __device__ __forceinline__ unsigned bsum(unsigned v, unsigned acc) {
#if __has_builtin(__builtin_amdgcn_sad_u8)
    return __builtin_amdgcn_sad_u8(v, 0u, acc);
#else
    return acc + (v & 0xFFu) + ((v >> 8) & 0xFFu) + ((v >> 16) & 0xFFu) + (v >> 24);
#endif
}

__global__ __launch_bounds__(256) void packw(const int* __restrict__ w,
                                             const int* __restrict__ bias) {
    int blk = blockIdx.x;
    if (blk < 144) {
        int i = blk * 256 + threadIdx.x;        // [k][c][t] flat, 36864
        if (i >= 64 * 64 * 9) return;
        int k = i / 576;
        int r = i - k * 576;
        int c = r / 9;
        int t = r - c * 9;
        unsigned v = (unsigned)w[i];
        g_wb[((0 * 9 + t) * 64 + k) * 64 + c] = (unsigned char)((v & 255u) ^ 0x80u);
        g_wb[((1 * 9 + t) * 64 + k) * 64 + c] = (unsigned char)(((v >> 8) & 255u) ^ 0x80u);
    } else {
        int k    = threadIdx.x >> 2;            // 4 threads per k
        int part = threadIdx.x & 3;
        int s0 = 0, s1 = 0;
        for (int j = part * 144; j < part * 144 + 144; ++j) {
            unsigned W = (unsigned)w[k * 576 + j];
            s0 += (int)(W & 255u);
            s1 += (int)((W >> 8) & 255u);
        }
        s0 += __shfl_xor(s0, 1); s0 += __shfl_xor(s0, 2);
        s1 += __shfl_xor(s1, 1); s1 += __shfl_xor(s1, 2);
        if (part == 0) {
            s0 -= 73728;                        // -128*576
            s1 -= 73728;
            unsigned ws = (unsigned)(s0 + 256 * s1);
            g_off[k] = (unsigned)bias[k] + 32896u * ws + 1082146816u * 576u;
        }
    }
}

// packx: grid 448 = 32 n x 14 rg; block packs 4 input rows into padded rows
// pr = ih+1, plus the border columns; rg==0/13 also fill padded rows 0/57.
__global__ __launch_bounds__(256) void packx(const int* __restrict__ x,
                                             unsigned char* __restrict__ pk,
                                             int* __restrict__ sp)
{
    const int blk = blockIdx.x;
    const int n = blk / 14, rg = blk - n * 14;
    const int tid = threadIdx.x;
    const int r4 = tid >> 6, rem = tid & 63;
    const int pq = rem >> 2, c4 = rem & 3;
    const int ih = rg * 4 + r4;                 // 0..55
    const int pr = ih + 1;
    unsigned char* cell0 = pk + (long)n * PKIMG + pr * PKROW;
    int* srow = sp + n * SIMG + pr * 58;
    const uint4 fillv = make_uint4(0x80808080u, 0x80808080u, 0x80808080u, 0x80808080u);

    if (pq < 14) {                              // interior quad-pixel task
        const int iw0 = pq * 4;
        const int* bp = x + (long)n * 64 * 3136 + ih * 56 + iw0;
        unsigned slo[4] = {0,0,0,0}, shi[4] = {0,0,0,0};
        unsigned lov[4][4], hiv[4][4];           // [cb][px]
#pragma unroll
        for (int cb = 0; cb < 4; ++cb) {         // ch = c4*16 + cb*4 + j
            v4i q0 = *(const v4i*)(bp + (c4 * 16 + cb * 4 + 0) * 3136);
            v4i q1 = *(const v4i*)(bp + (c4 * 16 + cb * 4 + 1) * 3136);
            v4i q2 = *(const v4i*)(bp + (c4 * 16 + cb * 4 + 2) * 3136);
            v4i q3 = *(const v4i*)(bp + (c4 * 16 + cb * 4 + 3) * 3136);
#pragma unroll
            for (int p = 0; p < 4; ++p) {
                unsigned t01 = __builtin_amdgcn_perm((unsigned)q1[p], (unsigned)q0[p], 0x05040100u);
                unsigned t23 = __builtin_amdgcn_perm((unsigned)q3[p], (unsigned)q2[p], 0x05040100u);
                unsigned lw  = __builtin_amdgcn_perm(t23, t01, 0x06040200u);
                unsigned hw  = __builtin_amdgcn_perm(t23, t01, 0x07050301u);
                slo[p] = bsum(lw, slo[p]);
                shi[p] = bsum(hw, shi[p]);
                lov[cb][p] = lw ^ 0x80808080u;
                hiv[cb][p] = hw ^ 0x80808080u;
            }
        }
        unsigned char* ob = cell0 + (iw0 + 1) * 128 + c4 * 16;
#pragma unroll
        for (int p = 0; p < 4; ++p) {
            *(uint4*)(ob + p * 128)      = make_uint4(lov[0][p], lov[1][p], lov[2][p], lov[3][p]);
            *(uint4*)(ob + p * 128 + 64) = make_uint4(hiv[0][p], hiv[1][p], hiv[2][p], hiv[3][p]);
        }
#pragma unroll
        for (int p = 0; p < 4; ++p) {
            int s = (int)(slo[p] + (shi[p] << 8));
            s += __shfl_xor(s, 1);
            s += __shfl_xor(s, 2);
            if (c4 == 0) srow[iw0 + 1 + p] = s - 2105344;   // -64*32896
        }
    } else {                                     // border columns pc = 0 / 57
        const int pc = (pq == 14) ? 0 : 57;
        unsigned char* ob = cell0 + pc * 128 + c4 * 16;
        *(uint4*)(ob)      = fillv;
        *(uint4*)(ob + 64) = fillv;
        if (c4 == 0) srow[pc] = -2105344;
    }

    const int br = (rg == 0) ? 0 : (rg == 13 ? 57 : -1);
    if (br >= 0) {                               // padded border row
        unsigned char* rb = pk + (long)n * PKIMG + br * PKROW;
        int* sb = sp + n * SIMG + br * 58;
        for (int j = tid; j < 58 * 8; j += 256) {
            const int cell = j >> 3, i = j & 7;
            *(uint4*)(rb + cell * 128 + i * 16) = fillv;
            if (i == 0) sb[cell] = -2105344;
        }
    }
}

// conv: grid 896 = 32 n x 14 rg x 2 ph; block = 4 waves (ktiles), one
// row-pair, 7 col-groups. No LDS, no barriers.
__global__ __launch_bounds__(256, 3) void conv(const unsigned char* __restrict__ pk,
                                               const int* __restrict__ sp,
                                               int* __restrict__ out)
{
    const int blk = blockIdx.x;
    const int q   = blk >> 3;
    const int rg  = q % 14;
    const int hi  = q / 14;                     // 0..7
    const int ph  = hi & 1;
    const int n   = (blk & 7) + 8 * (hi >> 1);
    const int tid = threadIdx.x;
    const int wid = tid >> 6;                   // ktile -> k base wid*16
    const int lane = tid & 63;
    const int lm  = lane & 15;
    const int lq  = lane >> 4;
    const int r8  = lm >> 3, c8 = lm & 7;       // pixel tile: 2 rows x 8 cols
    const int R   = 4 * rg + 2 * ph + r8;       // this lane's output row

    v4i wf[2][9];
#pragma unroll
    for (int l = 0; l < 2; ++l)
#pragma unroll
        for (int tp = 0; tp < 9; ++tp)
            wf[l][tp] = *(const v4i*)(g_wb +
                (((l * 9 + tp) * 64) + (wid * 16 + lm)) * 64 + lq * 16);
#pragma unroll
    for (int l = 0; l < 2; ++l)
#pragma unroll
        for (int tp = 0; tp < 9; ++tp)
            asm volatile("" : "+v"(wf[l][tp]));  // keep resident

    unsigned offv[4];
#pragma unroll
    for (int r = 0; r < 4; ++r) offv[r] = g_off[wid * 16 + lq * 4 + r];

    // 3 tap-row base pointers into packed x (padded: pr = R + dr, pc = c8 + dc)
    const unsigned char* p0 = pk + (long)n * PKIMG + R * PKROW + c8 * 128 + lq * 16;
    const unsigned char* p1 = p0 + PKROW;
    const unsigned char* p2 = p1 + PKROW;
    const int* sb = sp + n * SIMG + R * 58 + c8;

    const long ob0 = ((long)n * 64 + wid * 16 + lq * 4) * 3136 + (long)R * 56 + c8;

    for (int t = 0; t < 7; ++t) {
        v4i a00 = {0,0,0,0}, a01 = {0,0,0,0}, a10 = {0,0,0,0}, a11 = {0,0,0,0};
        __builtin_amdgcn_s_setprio(1);
#pragma unroll
        for (int dr = 0; dr < 3; ++dr) {
            const unsigned char* pr_ = (dr == 0) ? p0 : (dr == 1) ? p1 : p2;
#pragma unroll
            for (int dc = 0; dc < 3; ++dc) {
                v4i bl = *(const v4i*)(pr_ + dc * 128);
                v4i bh = *(const v4i*)(pr_ + dc * 128 + 64);
                const int tap = dr * 3 + dc;
                a00 = __builtin_amdgcn_mfma_i32_16x16x64_i8(wf[0][tap], bl, a00, 0, 0, 0);
                a01 = __builtin_amdgcn_mfma_i32_16x16x64_i8(wf[0][tap], bh, a01, 0, 0, 0);
                a10 = __builtin_amdgcn_mfma_i32_16x16x64_i8(wf[1][tap], bl, a10, 0, 0, 0);
                a11 = __builtin_amdgcn_mfma_i32_16x16x64_i8(wf[1][tap], bh, a11, 0, 0, 0);
            }
        }
        __builtin_amdgcn_s_setprio(0);

        int Q = 0;
#pragma unroll
        for (int dr = 0; dr < 3; ++dr)
#pragma unroll
            for (int dc = 0; dc < 3; ++dc)
                Q += sb[dr * 58 + dc];
        const unsigned qq = 32896u * (unsigned)Q;

        const long ob = ob0 + t * 8;
#pragma unroll
        for (int r = 0; r < 4; ++r) {
            unsigned val = (unsigned)a00[r]
                         + (((unsigned)a01[r] + (unsigned)a10[r]) << 8)
                         + ((unsigned)a11[r] << 16)
                         + qq + offv[r];
            out[ob + (long)r * 3136] = (int)val;
        }

        p0 += 8 * 128; p1 += 8 * 128; p2 += 8 * 128; sb += 8;
    }
}

// ---------------- fallback: proven R16 fused kernel ----------------
__global__ __launch_bounds__(256, 2) void secconv(const int* __restrict__ x,
                                                  int* __restrict__ out)
{
    __shared__ unsigned char sx[6 * LROW];
    __shared__ int ss[6 * 58];

    const int tid  = threadIdx.x;
    const int blk  = blockIdx.x;
    const int q    = blk >> 3;
    const int rg   = q % 14;
    const int n    = (blk & 7) + 8 * (q / 14);
    const int wid  = tid >> 6;
    const int lane = tid & 63;
    const int lm   = lane & 15;
    const int lq   = lane >> 4;
    const int kp   = wid & 1;
    const int ph   = wid >> 1;
    const int kbase = kp * 32;

    const uint4 fillv = make_uint4(0x80808080u, 0x80808080u, 0x80808080u, 0x80808080u);
    if (tid < 96) {
        const int cell = tid >> 3, i = tid & 7;
        const int pr = cell >> 1, pc = (cell & 1) * 57;
        *(uint4*)(sx + pr * LROW + pc * LCOL + i * 16) = fillv;
        if (i == 0) ss[pr * 58 + pc] = -2105344;
    }
    const int brow = (rg == 0) ? 0 : (rg == 13 ? 5 : -1);
    if (brow >= 0) {
        for (int j = tid; j < 464; j += 256) {
            const int cell = j >> 3, i = j & 7;
            *(uint4*)(sx + brow * LROW + cell * LCOL + i * 16) = fillv;
            if (i == 0) ss[brow * 58 + cell] = -2105344;
        }
    }

    const int* bp = x + (long)n * 64 * 3136;
    for (int task = tid; task < 336; task += 256) {
        const int pr = task / 56;
        const int rr = task - pr * 56;
        const int pq = rr >> 2;
        const int c4 = rr & 3;
        const int ih = 4 * rg - 1 + pr;
        if ((unsigned)ih < 56u) {
            const int voff = c4 * 16 * 3136 + ih * 56 + pq * 4;
            unsigned slo[4] = {0,0,0,0}, shi[4] = {0,0,0,0};
            unsigned lov[4][4], hiv[4][4];
#pragma unroll
            for (int cb = 0; cb < 4; ++cb) {
                v4i q0 = *(const v4i*)(bp + (cb * 4 + 0) * 3136 + voff);
                v4i q1 = *(const v4i*)(bp + (cb * 4 + 1) * 3136 + voff);
                v4i q2 = *(const v4i*)(bp + (cb * 4 + 2) * 3136 + voff);
                v4i q3 = *(const v4i*)(bp + (cb * 4 + 3) * 3136 + voff);
#pragma unroll
                for (int p = 0; p < 4; ++p) {
                    unsigned t01 = __builtin_amdgcn_perm((unsigned)q1[p], (unsigned)q0[p], 0x05040100u);
                    unsigned t23 = __builtin_amdgcn_perm((unsigned)q3[p], (unsigned)q2[p], 0x05040100u);
                    unsigned lw  = __builtin_amdgcn_perm(t23, t01, 0x06040200u);
                    unsigned hw  = __builtin_amdgcn_perm(t23, t01, 0x07050301u);
                    slo[p] = bsum(lw, slo[p]);
                    shi[p] = bsum(hw, shi[p]);
                    lov[cb][p] = lw ^ 0x80808080u;
                    hiv[cb][p] = hw ^ 0x80808080u;
                }
            }
            unsigned char* ob = sx + pr * LROW + (pq * 4 + 1) * LCOL + c4 * 16;
#pragma unroll
            for (int p = 0; p < 4; ++p) {
                *(uint4*)(ob + p * LCOL)      = make_uint4(lov[0][p], lov[1][p], lov[2][p], lov[3][p]);
                *(uint4*)(ob + p * LCOL + 64) = make_uint4(hiv[0][p], hiv[1][p], hiv[2][p], hiv[3][p]);
            }
#pragma unroll
            for (int p = 0; p < 4; ++p) {
                int s = (int)(slo[p] + (shi[p] << 8));
                s += __shfl_xor(s, 1);
                s += __shfl_xor(s, 2);
                if (c4 == 0) ss[pr * 58 + pq * 4 + 1 + p] = s - 2105344;
            }
        }
    }

    v4i wf[2][2][9];
#pragma unroll
    for (int kt = 0; kt < 2; ++kt)
#pragma unroll
        for (int l = 0; l < 2; ++l)
#pragma unroll
            for (int t = 0; t < 9; ++t)
                wf[kt][l][t] = *(const v4i*)(g_wb +
                    ((l * 9 + t) * 64 + (kbase + kt * 16 + lm)) * 64 + lq * 16);
    unsigned offv[2][4];
#pragma unroll
    for (int kt = 0; kt < 2; ++kt)
#pragma unroll
        for (int r = 0; r < 4; ++r)
            offv[kt][r] = g_off[kbase + kt * 16 + lq * 4 + r];

    __syncthreads();

    const int r8 = lm >> 3, c8 = lm & 7;
    const int lrow = 2 * ph + r8;
    const unsigned char* lbase = sx + lrow * LROW + c8 * LCOL + lq * 16;

    for (int t = 0; t < 7; ++t) {
        const unsigned char* tb = lbase + t * 8 * LCOL;
        v4i a00[2] = {{0,0,0,0},{0,0,0,0}}, a01[2] = {{0,0,0,0},{0,0,0,0}};
        v4i a10[2] = {{0,0,0,0},{0,0,0,0}}, a11[2] = {{0,0,0,0},{0,0,0,0}};
        __builtin_amdgcn_s_setprio(1);
#pragma unroll
        for (int tap = 0; tap < 9; ++tap) {
            const int dr = tap / 3, dc = tap - (tap / 3) * 3;
            const unsigned char* pp = tb + dr * LROW + dc * LCOL;
            v4i bl = *(const v4i*)(pp);
            v4i bh = *(const v4i*)(pp + 64);
#pragma unroll
            for (int kt = 0; kt < 2; ++kt) {
                a00[kt] = __builtin_amdgcn_mfma_i32_16x16x64_i8(wf[kt][0][tap], bl, a00[kt], 0, 0, 0);
                a01[kt] = __builtin_amdgcn_mfma_i32_16x16x64_i8(wf[kt][0][tap], bh, a01[kt], 0, 0, 0);
                a10[kt] = __builtin_amdgcn_mfma_i32_16x16x64_i8(wf[kt][1][tap], bl, a10[kt], 0, 0, 0);
                a11[kt] = __builtin_amdgcn_mfma_i32_16x16x64_i8(wf[kt][1][tap], bh, a11[kt], 0, 0, 0);
            }
        }
        __builtin_amdgcn_s_setprio(0);

        const int pc = t * 8 + c8;
        int Q = 0;
#pragma unroll
        for (int dr = 0; dr < 3; ++dr)
#pragma unroll
            for (int dc = 0; dc < 3; ++dc)
                Q += ss[(lrow + dr) * 58 + pc + dc];
        const unsigned qq = 32896u * (unsigned)Q;

        const long pix = (long)(4 * rg + lrow) * 56 + pc;
#pragma unroll
        for (int kt = 0; kt < 2; ++kt) {
            const long ob = ((long)n * 64 + kbase + kt * 16 + lq * 4) * 3136 + pix;
#pragma unroll
            for (int r = 0; r < 4; ++r) {
                unsigned val = (unsigned)a00[kt][r]
                             + (((unsigned)a01[kt][r] + (unsigned)a10[kt][r]) << 8)
                             + ((unsigned)a11[kt][r] << 16)
                             + qq + offv[kt][r];
                out[ob + (long)r * 3136] = (int)val;
            }
        }
    }
}

extern "C" void kernel_launch(void* const* d_in, const int* in_sizes, int n_in,
                              void* d_out, int out_size, void* d_ws, size_t ws_size,
                              hipStream_t stream)
{
    const int* x    = (const int*)d_in[0];
    const int* w    = (const int*)d_in[1];
    const int* bias = (const int*)d_in[2];
    int* out        = (int*)d_out;

    packw<<<dim3(145), dim3(256), 0, stream>>>(w, bias);
    if (d_ws && ws_size >= (size_t)WS_NEED) {
        unsigned char* pk = (unsigned char*)d_ws;
        int* sp = (int*)((char*)d_ws + 32L * PKIMG);
        packx<<<dim3(448), dim3(256), 0, stream>>>(x, pk, sp);
        conv <<<dim3(896), dim3(256), 0, stream>>>(pk, sp, out);
    } else {
        secconv<<<dim3(448), dim3(256), 0, stream>>>(x, out);
    }
}

// Round 10
// 99.761 us; speedup vs baseline: 1.5082x; 1.5082x over previous
//
#include <hip/hip_runtime.h>

// SecConv2d over Z_{2^32} via i8 MFMA, 4-chain biased-operand scheme (exact).
//   s(x) = x_byte - 128 per limb  => X = s(al) + 256*s(ah) + 32896
//   s(w) likewise                 => W = s0 + 256*s1 + 32896
//   out = P00 + (P01+P10)<<8 + P11<<16 + 32896*Q[p] + K[k]   (mod 2^32)
//   Q = 3x3 box sum of S[p], S[p] = sum_c (X_true - 32896) (border cells are
//   bytes 0x80 == s=-128 -> uniformly "interior with x=0", exact).
//
// R19: fused (R9/R16 skeleton). The decisive counter from R14/R18: VGPR=84/64
// with wf needing 72+ regs => compiler REMATERIALIZES weight-fragment loads
// from g_wb inside the tap loop (empty-asm pin doesn't stop remat of
// read-only global loads). Fixes:
//  (1) wf loaded via OPAQUE inline-asm global_load_dwordx4 ("=v") -- asm
//      results cannot be rematerialized; wf must stay resident.
//  (2) wave = one 16-k tile x all 4 output rows (mapping proven in R14/R18):
//      wf 144->72 regs, acc 32; fits the budget that (1) demands.
//  (3) pack loads hoisted: all 16 dwordx4 per task in flight before math.
//  Border fill / pack math / Q-sharing / stores / setprio: R16 verbatim.

typedef int v4i __attribute__((ext_vector_type(4)));

#define LCOL 144               // LDS col stride (128 B payload + 16 pad)
#define LROW (58 * LCOL)       // 8352 B per LDS halo row

__device__ __align__(16) unsigned char g_wb[2 * 9 * 64 * 64];
__device__ unsigned g_off[64];

static __device__ __forceinline__ unsigned bsum(unsigned v, unsigned acc) {
#if __has_builtin(__builtin_amdgcn_sad_u8)
    return __builtin_amdgcn_sad_u8(v, 0u, acc);
#else
    return acc + (v & 0xFFu) + ((v >> 8) & 0xFFu) + ((v >> 16) & 0xFFu) + (v >> 24);
#endif
}

__global__ __launch_bounds__(256) void packw(const int* __restrict__ w,
                                             const int* __restrict__ bias) {
    int blk = blockIdx.x;
    if (blk < 144) {
        int i = blk * 256 + threadIdx.x;        // [k][c][t] flat, 36864
        if (i >= 64 * 64 * 9) return;
        int k = i / 576;
        int r = i - k * 576;
        int c = r / 9;
        int t = r - c * 9;
        unsigned v = (unsigned)w[i];
        g_wb[((0 * 9 + t) * 64 + k) * 64 + c] = (unsigned char)((v & 255u) ^ 0x80u);
        g_wb[((1 * 9 + t) * 64 + k) * 64 + c] = (unsigned char)(((v >> 8) & 255u) ^ 0x80u);
    } else {
        int k    = threadIdx.x >> 2;            // 4 threads per k
        int part = threadIdx.x & 3;
        int s0 = 0, s1 = 0;
        for (int j = part * 144; j < part * 144 + 144; ++j) {
            unsigned W = (unsigned)w[k * 576 + j];
            s0 += (int)(W & 255u);
            s1 += (int)((W >> 8) & 255u);
        }
        s0 += __shfl_xor(s0, 1); s0 += __shfl_xor(s0, 2);
        s1 += __shfl_xor(s1, 1); s1 += __shfl_xor(s1, 2);
        if (part == 0) {
            s0 -= 73728;                        // -128*576
            s1 -= 73728;
            unsigned ws = (unsigned)(s0 + 256 * s1);
            g_off[k] = (unsigned)bias[k] + 32896u * ws + 1082146816u * 576u;
        }
    }
}

__global__ __launch_bounds__(256, 2) void secconv(const int* __restrict__ x,
                                                  int* __restrict__ out)
{
    __shared__ unsigned char sx[6 * LROW];      // 50112 B
    __shared__ int ss[6 * 58];                  // S-plane, 6 halo rows

    const int tid  = threadIdx.x;
    const int blk  = blockIdx.x;                // 448 = 8 xcd * 56
    const int q    = blk >> 3;
    const int rg   = q % 14;                    // row-group of 4 output rows
    const int n    = (blk & 7) + 8 * (q / 14);
    const int wid  = tid >> 6;                  // ktile 0..3 -> k base wid*16
    const int lane = tid & 63;
    const int lm   = lane & 15;
    const int lq   = lane >> 4;
    const int r8   = lm >> 3;                   // pixel tile: 2 rows x 8 cols
    const int c8   = lm & 7;

    // ---- border fill: halo cols pc=0,57 + border row if any (R16) ----
    const uint4 fillv = make_uint4(0x80808080u, 0x80808080u, 0x80808080u, 0x80808080u);
    if (tid < 96) {
        const int cell = tid >> 3, i = tid & 7;
        const int pr = cell >> 1, pc = (cell & 1) * 57;
        *(uint4*)(sx + pr * LROW + pc * LCOL + i * 16) = fillv;
        if (i == 0) ss[pr * 58 + pc] = -2105344;     // -64*32896
    }
    const int brow = (rg == 0) ? 0 : (rg == 13 ? 5 : -1);
    if (brow >= 0) {
        for (int j = tid; j < 464; j += 256) {       // 58 cells x 8 stores
            const int cell = j >> 3, i = j & 7;
            *(uint4*)(sx + brow * LROW + cell * LCOL + i * 16) = fillv;
            if (i == 0) ss[brow * 58 + cell] = -2105344;
        }
    }

    // ---- pack v3 (R16) with fully-hoisted loads ----
    const int* bp = x + (long)n * 64 * 3136;    // batch base (symbolic)
    for (int task = tid; task < 336; task += 256) {
        const int pr = task / 56;
        const int rr = task - pr * 56;
        const int pq = rr >> 2;
        const int c4 = rr & 3;
        const int ih = 4 * rg - 1 + pr;
        if ((unsigned)ih < 56u) {                    // interior row
            const int voff = c4 * 16 * 3136 + ih * 56 + pq * 4;
            v4i qv[16];
#pragma unroll
            for (int cj = 0; cj < 16; ++cj)          // 16 independent loads
                qv[cj] = *(const v4i*)(bp + cj * 3136 + voff);
            unsigned slo[4] = {0, 0, 0, 0}, shi[4] = {0, 0, 0, 0};
            unsigned lov[4][4], hiv[4][4];           // [cb][px]
#pragma unroll
            for (int cb = 0; cb < 4; ++cb) {
#pragma unroll
                for (int p = 0; p < 4; ++p) {
                    unsigned t01 = __builtin_amdgcn_perm((unsigned)qv[cb * 4 + 1][p], (unsigned)qv[cb * 4 + 0][p], 0x05040100u);
                    unsigned t23 = __builtin_amdgcn_perm((unsigned)qv[cb * 4 + 3][p], (unsigned)qv[cb * 4 + 2][p], 0x05040100u);
                    unsigned lw  = __builtin_amdgcn_perm(t23, t01, 0x06040200u);
                    unsigned hw  = __builtin_amdgcn_perm(t23, t01, 0x07050301u);
                    slo[p] = bsum(lw, slo[p]);
                    shi[p] = bsum(hw, shi[p]);
                    lov[cb][p] = lw ^ 0x80808080u;
                    hiv[cb][p] = hw ^ 0x80808080u;
                }
            }
            unsigned char* ob = sx + pr * LROW + (pq * 4 + 1) * LCOL + c4 * 16;
#pragma unroll
            for (int p = 0; p < 4; ++p) {
                *(uint4*)(ob + p * LCOL)      = make_uint4(lov[0][p], lov[1][p], lov[2][p], lov[3][p]);
                *(uint4*)(ob + p * LCOL + 64) = make_uint4(hiv[0][p], hiv[1][p], hiv[2][p], hiv[3][p]);
            }
#pragma unroll
            for (int p = 0; p < 4; ++p) {
                int s = (int)(slo[p] + (shi[p] << 8));
                s += __shfl_xor(s, 1);
                s += __shfl_xor(s, 2);
                if (c4 == 0) ss[pr * 58 + pq * 4 + 1 + p] = s - 2105344;
            }
        }
    }

    // ---- resident weight fragments via OPAQUE loads: 2 limbs x 9 taps ----
    v4i wf[2][9];
#pragma unroll
    for (int l = 0; l < 2; ++l)
#pragma unroll
        for (int tp = 0; tp < 9; ++tp) {
            const unsigned char* a = g_wb +
                (((l * 9 + tp) * 64) + (wid * 16 + lm)) * 64 + lq * 16;
            asm volatile("global_load_dwordx4 %0, %1, off"
                         : "=v"(wf[l][tp]) : "v"(a));
        }
    unsigned offv[4];
#pragma unroll
    for (int r = 0; r < 4; ++r) offv[r] = g_off[wid * 16 + lq * 4 + r];
    asm volatile("s_waitcnt vmcnt(0)" ::: "memory");

    __syncthreads();

    // ---- MFMA: 7 col-groups x 9 taps x 2 row-pairs x 4 limb chains ----
    const unsigned char* lbase = sx + r8 * LROW + c8 * LCOL + lq * 16;

    for (int t = 0; t < 7; ++t) {
        const unsigned char* tb = lbase + t * 8 * LCOL;
        v4i a00[2] = {{0,0,0,0},{0,0,0,0}}, a01[2] = {{0,0,0,0},{0,0,0,0}};
        v4i a10[2] = {{0,0,0,0},{0,0,0,0}}, a11[2] = {{0,0,0,0},{0,0,0,0}};
        __builtin_amdgcn_s_setprio(1);
#pragma unroll
        for (int tap = 0; tap < 9; ++tap) {
            const int dr = tap / 3, dc = tap - (tap / 3) * 3;
            const unsigned char* pp = tb + dr * LROW + dc * LCOL;
            v4i bl0 = *(const v4i*)(pp);
            v4i bh0 = *(const v4i*)(pp + 64);
            v4i bl1 = *(const v4i*)(pp + 2 * LROW);
            v4i bh1 = *(const v4i*)(pp + 2 * LROW + 64);
            a00[0] = __builtin_amdgcn_mfma_i32_16x16x64_i8(wf[0][tap], bl0, a00[0], 0, 0, 0);
            a01[0] = __builtin_amdgcn_mfma_i32_16x16x64_i8(wf[0][tap], bh0, a01[0], 0, 0, 0);
            a10[0] = __builtin_amdgcn_mfma_i32_16x16x64_i8(wf[1][tap], bl0, a10[0], 0, 0, 0);
            a11[0] = __builtin_amdgcn_mfma_i32_16x16x64_i8(wf[1][tap], bh0, a11[0], 0, 0, 0);
            a00[1] = __builtin_amdgcn_mfma_i32_16x16x64_i8(wf[0][tap], bl1, a00[1], 0, 0, 0);
            a01[1] = __builtin_amdgcn_mfma_i32_16x16x64_i8(wf[0][tap], bh1, a01[1], 0, 0, 0);
            a10[1] = __builtin_amdgcn_mfma_i32_16x16x64_i8(wf[1][tap], bl1, a10[1], 0, 0, 0);
            a11[1] = __builtin_amdgcn_mfma_i32_16x16x64_i8(wf[1][tap], bh1, a11[1], 0, 0, 0);
        }
        __builtin_amdgcn_s_setprio(0);

        const int pc = t * 8 + c8;
        int cs[5];
#pragma unroll
        for (int j = 0; j < 5; ++j)
            cs[j] = ss[(r8 + j) * 58 + pc] + ss[(r8 + j) * 58 + pc + 1] + ss[(r8 + j) * 58 + pc + 2];
        const unsigned qq0 = 32896u * (unsigned)(cs[0] + cs[1] + cs[2]);
        const unsigned qq1 = 32896u * (unsigned)(cs[2] + cs[3] + cs[4]);

#pragma unroll
        for (int rp = 0; rp < 2; ++rp) {
            const unsigned qq = rp ? qq1 : qq0;
            const long ob = ((long)n * 64 + wid * 16 + lq * 4) * 3136
                          + (long)(4 * rg + 2 * rp + r8) * 56 + pc;
#pragma unroll
            for (int r = 0; r < 4; ++r) {
                unsigned val = (unsigned)a00[rp][r]
                             + (((unsigned)a01[rp][r] + (unsigned)a10[rp][r]) << 8)
                             + ((unsigned)a11[rp][r] << 16)
                             + qq + offv[r];
                out[ob + (long)r * 3136] = (int)val;
            }
        }
    }
}

extern "C" void kernel_launch(void* const* d_in, const int* in_sizes, int n_in,
                              void* d_out, int out_size, void* d_ws, size_t ws_size,
                              hipStream_t stream)
{
    const int* x    = (const int*)d_in[0];
    const int* w    = (const int*)d_in[1];
    const int* bias = (const int*)d_in[2];
    int* out        = (int*)d_out;

    packw  <<<dim3(145), dim3(256), 0, stream>>>(w, bias);
    secconv<<<dim3(448), dim3(256), 0, stream>>>(x, out);
}